// Round 4
// baseline (1651.481 us; speedup 1.0000x reference)
//
#include <hip/hip_runtime.h>
#include <hip/hip_bf16.h>
#include <stdint.h>

typedef __bf16 bf16_t;
typedef __bf16 bf16x4 __attribute__((ext_vector_type(4)));
typedef __bf16 bf16x8 __attribute__((ext_vector_type(8)));
typedef float f32x16 __attribute__((ext_vector_type(16)));

#define LDS_CAST(p) ((__attribute__((address_space(3))) void*)(p))
#define GLB_CAST(p) ((const __attribute__((address_space(1))) void*)(p))

__device__ __forceinline__ void gl_lds16(const void* g, void* l) {
  __builtin_amdgcn_global_load_lds(GLB_CAST(g), LDS_CAST(l), 16, 0, 0);
}

#define MFMA32(a,b,c) __builtin_amdgcn_mfma_f32_32x32x16_bf16((a),(b),(c),0,0,0)
#define BARRIER() __builtin_amdgcn_s_barrier()
#define LGKM0() asm volatile("s_waitcnt lgkmcnt(0)" ::: "memory")

template<int N> __device__ __forceinline__ void vmw() {
  if constexpr (N == 6)      asm volatile("s_waitcnt vmcnt(6)" ::: "memory");
  else if constexpr (N == 2) asm volatile("s_waitcnt vmcnt(2)" ::: "memory");
  else if constexpr (N == 0) asm volatile("s_waitcnt vmcnt(0)" ::: "memory");
  // N < 0: no wait
}

static constexpr int M_TOT = 4096, H_DIM = 4096, I_DIM = 14336;

// ---------------------------------------------------------------------------
// fp32 -> bf16 conversion (float4 in, bf16x4 out), grid-stride
// ---------------------------------------------------------------------------
__global__ __launch_bounds__(256)
void k_conv(const float4* __restrict__ src, bf16x4* __restrict__ dst, long n4)
{
  long stride = (long)gridDim.x * blockDim.x;
  for (long i = (long)blockIdx.x * blockDim.x + threadIdx.x; i < n4; i += stride) {
    float4 v = src[i];
    bf16x4 o;
    o[0] = (bf16_t)v.x; o[1] = (bf16_t)v.y; o[2] = (bf16_t)v.z; o[3] = (bf16_t)v.w;
    dst[i] = o;
  }
}

// ===========================================================================
// GEMM1 phase: 6 ds_read_b128 + optional 2 gl_lds stage + 8 x mfma 32x32x16.
// STG: 0 none, 1 stage X halves, 2 stage G+U. WAIT: vmcnt(N) after MFMA.
// ===========================================================================
template<int STG, int WAIT>
__device__ __forceinline__ void g1_phase(
    const char* bb, int kx, char* sb,
    const bf16_t* gXk, const bf16_t* gGk, const bf16_t* gUk, size_t xh,
    int offA, int offG, int offU, f32x16 (&accg)[4], f32x16 (&accu)[4])
{
  if constexpr (STG == 1) { gl_lds16(gXk, sb); gl_lds16(gXk + xh, sb + 8192); }
  if constexpr (STG == 2) { gl_lds16(gGk, sb + 16384); gl_lds16(gUk, sb + 24576); }
  bf16x8 av[4], bgv, buv;
#pragma unroll
  for (int f = 0; f < 4; ++f)
    av[f] = *(const bf16x8*)(bb + ((offA + f * 2048) ^ kx));
  bgv = *(const bf16x8*)(bb + (offG ^ kx));
  buv = *(const bf16x8*)(bb + (offU ^ kx));
  BARRIER(); LGKM0();
  __builtin_amdgcn_s_setprio(1);
#pragma unroll
  for (int m = 0; m < 4; ++m) {
    accg[m] = MFMA32(av[m], bgv, accg[m]);
    accu[m] = MFMA32(av[m], buv, accu[m]);
  }
  __builtin_amdgcn_s_setprio(0);
  vmw<WAIT>();
  BARRIER();
}

// GEMM1: A[M,I] = silu(X Wg^T) * (X Wu^T). BM=256, BN=128, BK=32.
// 8 waves (2M x 4N); per-wave G 128x32 + U 128x32 via 32x32x16 MFMA.
// 4 LDS buffers x 32 KiB (A 16K | G 8K | U 8K), lead 3 tiles, vmcnt(6)/tile.
__global__ __launch_bounds__(512, 2)
void k_gateup8(const bf16_t* __restrict__ X, const bf16_t* __restrict__ Wg,
               const bf16_t* __restrict__ Wu, bf16_t* __restrict__ Aout)
{
  __shared__ __align__(1024) char lds[131072];
  const int tid = threadIdx.x, wave = tid >> 6, lane = tid & 63;
  const int rowb = lane & 31, hi = lane >> 5;
  const int xm = ((rowb >> 3) & 1) << 5;     // read-side swizzle (bit5 ^ row-bit3)
  const int wm = wave >> 2, wn = wave & 3;

  const int bid = blockIdx.x;                 // grid = 16*112 = 1792 (%8==0)
  const int swz = (bid & 7) * 224 + (bid >> 3);
  const int tm = swz / 112, tn = swz % 112;

  const int srow  = tid >> 2;                                   // 0..127
  const int scolb = ((tid & 3) * 16) ^ (((tid >> 5) & 1) << 5); // pre-swizzled src col

  const bf16_t* gX = X  + (size_t)(tm * 256 + srow) * H_DIM + (scolb >> 1);
  const bf16_t* gG = Wg + (size_t)(tn * 128 + srow) * H_DIM + (scolb >> 1);
  const bf16_t* gU = Wu + (size_t)(tn * 128 + srow) * H_DIM + (scolb >> 1);
  const size_t xh = (size_t)128 * H_DIM;

  // fragment byte offsets within a 32 KiB buffer (k-slot toggled by ^32)
  const int ck  = (hi * 16) ^ xm;
  const int offA = (wm * 128 + rowb) * 64 + ck;            // + m*2048
  const int offG = 16384 + (wn * 32 + rowb) * 64 + ck;
  const int offU = offG + 8192;

  f32x16 accg[4], accu[4];
#pragma unroll
  for (int m = 0; m < 4; ++m)
#pragma unroll
    for (int r = 0; r < 16; ++r) { accg[m][r] = 0.f; accu[m][r] = 0.f; }

#pragma unroll
  for (int t = 0; t < 3; ++t) {
    char* lb = lds + t * 32768 + wave * 1024;
    gl_lds16(gX + t * 32,      lb);
    gl_lds16(gX + xh + t * 32, lb + 8192);
    gl_lds16(gG + t * 32,      lb + 16384);
    gl_lds16(gU + t * 32,      lb + 24576);
  }
  vmw<8 - 2>(); BARRIER();   // vmcnt(6): leaves tiles 1,2 partially in flight; tile0 forced

  const int NT = H_DIM / 32;                  // 128
  for (int T = 0; T < NT - 3; ++T) {
    const char* bb = lds + (T & 3) * 32768;
    char* sb = lds + ((T + 3) & 3) * 32768 + wave * 1024;
    const int kc = (T + 3) * 32;
    g1_phase<1, -1>(bb, 0,  sb, gX + kc, gG + kc, gU + kc, xh, offA, offG, offU, accg, accu);
    g1_phase<2,  6>(bb, 32, sb, gX + kc, gG + kc, gU + kc, xh, offA, offG, offU, accg, accu);
  }
  { const char* bb = lds + ((NT - 3) & 3) * 32768;
    g1_phase<0, -1>(bb, 0, lds, gX, gG, gU, xh, offA, offG, offU, accg, accu);
    g1_phase<0,  2>(bb, 32, lds, gX, gG, gU, xh, offA, offG, offU, accg, accu); }
  { const char* bb = lds + ((NT - 2) & 3) * 32768;
    g1_phase<0, -1>(bb, 0, lds, gX, gG, gU, xh, offA, offG, offU, accg, accu);
    g1_phase<0,  0>(bb, 32, lds, gX, gG, gU, xh, offA, offG, offU, accg, accu); }
  { const char* bb = lds + ((NT - 1) & 3) * 32768;
    g1_phase<0, -1>(bb, 0, lds, gX, gG, gU, xh, offA, offG, offU, accg, accu);
    g1_phase<0, -1>(bb, 32, lds, gX, gG, gU, xh, offA, offG, offU, accg, accu); }

  // C/D: col = lane&31, row = (r&3) + 8*(r>>2) + 4*(lane>>5)   [m74/m101]
  const int r0 = tm * 256 + wm * 128 + 4 * hi;
  const int c0 = tn * 128 + wn * 32 + rowb;
#pragma unroll
  for (int m = 0; m < 4; ++m)
#pragma unroll
    for (int r = 0; r < 16; ++r) {
      const int row = r0 + m * 32 + (r & 3) + 8 * (r >> 2);
      float g = accg[m][r];
      float u = accu[m][r];
      float s = g / (1.0f + __expf(-g));
      Aout[(size_t)row * I_DIM + c0] = (bf16_t)(s * u);
    }
}

// ===========================================================================
// GEMM2 phase: 6 ds_read_b128 + optional 2 gl_lds + 8 x mfma 32x32x16.
// ===========================================================================
template<int STG, int WAIT>
__device__ __forceinline__ void g2_phase(
    const char* bb, int kx, char* sb,
    const bf16_t* gAk, const bf16_t* gBk, size_t hI,
    int offA, int offB, f32x16 (&acc)[4][2])
{
  if constexpr (STG == 1) { gl_lds16(gAk, sb); gl_lds16(gAk + hI, sb + 8192); }
  if constexpr (STG == 2) { gl_lds16(gBk, sb + 16384); gl_lds16(gBk + hI, sb + 24576); }
  bf16x8 av[4], bv[2];
#pragma unroll
  for (int f = 0; f < 4; ++f)
    av[f] = *(const bf16x8*)(bb + ((offA + f * 2048) ^ kx));
#pragma unroll
  for (int n = 0; n < 2; ++n)
    bv[n] = *(const bf16x8*)(bb + ((offB + n * 2048) ^ kx));
  BARRIER(); LGKM0();
  __builtin_amdgcn_s_setprio(1);
#pragma unroll
  for (int m = 0; m < 4; ++m)
#pragma unroll
    for (int n = 0; n < 2; ++n)
      acc[m][n] = MFMA32(av[m], bv[n], acc[m][n]);
  __builtin_amdgcn_s_setprio(0);
  vmw<WAIT>();
  BARRIER();
}

// GEMM2: D[M,H] = A Wd^T. BM=BN=256, BK=32, K=I_DIM. Per-wave 128x64.
__global__ __launch_bounds__(512, 2)
void k_down8(const bf16_t* __restrict__ Aa, const bf16_t* __restrict__ Wd,
             float* __restrict__ D)
{
  __shared__ __align__(1024) char lds[131072];
  const int tid = threadIdx.x, wave = tid >> 6, lane = tid & 63;
  const int rowb = lane & 31, hi = lane >> 5;
  const int xm = ((rowb >> 3) & 1) << 5;
  const int wm = wave >> 2, wn = wave & 3;

  const int bid = blockIdx.x;                 // grid = 256 (%8==0)
  const int swz = (bid & 7) * 32 + (bid >> 3);
  const int tm = swz >> 4, tn = swz & 15;

  const int srow  = tid >> 2;
  const int scolb = ((tid & 3) * 16) ^ (((tid >> 5) & 1) << 5);

  const bf16_t* gA = Aa + (size_t)(tm * 256 + srow) * I_DIM + (scolb >> 1);
  const bf16_t* gB = Wd + (size_t)(tn * 256 + srow) * I_DIM + (scolb >> 1);
  const size_t hI = (size_t)128 * I_DIM;

  const int ck  = (hi * 16) ^ xm;
  const int offA = (wm * 128 + rowb) * 64 + ck;             // + m*2048
  const int offB = 16384 + (wn * 64 + rowb) * 64 + ck;      // + n*2048

  f32x16 acc[4][2];
#pragma unroll
  for (int m = 0; m < 4; ++m)
#pragma unroll
    for (int n = 0; n < 2; ++n)
#pragma unroll
      for (int r = 0; r < 16; ++r) acc[m][n][r] = 0.f;

#pragma unroll
  for (int t = 0; t < 3; ++t) {
    char* lb = lds + t * 32768 + wave * 1024;
    gl_lds16(gA + t * 32,      lb);
    gl_lds16(gA + hI + t * 32, lb + 8192);
    gl_lds16(gB + t * 32,      lb + 16384);
    gl_lds16(gB + hI + t * 32, lb + 24576);
  }
  vmw<6>(); BARRIER();

  const int NT = I_DIM / 32;                  // 448
  for (int T = 0; T < NT - 3; ++T) {
    const char* bb = lds + (T & 3) * 32768;
    char* sb = lds + ((T + 3) & 3) * 32768 + wave * 1024;
    const int kc = (T + 3) * 32;
    g2_phase<1, -1>(bb, 0,  sb, gA + kc, gB + kc, hI, offA, offB, acc);
    g2_phase<2,  6>(bb, 32, sb, gA + kc, gB + kc, hI, offA, offB, acc);
  }
  { const char* bb = lds + ((NT - 3) & 3) * 32768;
    g2_phase<0, -1>(bb, 0, lds, gA, gB, hI, offA, offB, acc);
    g2_phase<0,  2>(bb, 32, lds, gA, gB, hI, offA, offB, acc); }
  { const char* bb = lds + ((NT - 2) & 3) * 32768;
    g2_phase<0, -1>(bb, 0, lds, gA, gB, hI, offA, offB, acc);
    g2_phase<0,  0>(bb, 32, lds, gA, gB, hI, offA, offB, acc); }
  { const char* bb = lds + ((NT - 1) & 3) * 32768;
    g2_phase<0, -1>(bb, 0, lds, gA, gB, hI, offA, offB, acc);
    g2_phase<0, -1>(bb, 32, lds, gA, gB, hI, offA, offB, acc); }

  const int r0 = tm * 256 + wm * 128 + 4 * hi;
  const int c0 = tn * 256 + wn * 64 + rowb;
#pragma unroll
  for (int m = 0; m < 4; ++m)
#pragma unroll
    for (int n = 0; n < 2; ++n)
#pragma unroll
      for (int r = 0; r < 16; ++r) {
        const int row = r0 + m * 32 + (r & 3) + 8 * (r >> 2);
        D[(size_t)row * H_DIM + c0 + n * 32] = acc[m][n][r];
      }
}

// ---------------------------------------------------------------------------
extern "C" void kernel_launch(void* const* d_in, const int* in_sizes, int n_in,
                              void* d_out, int out_size, void* d_ws, size_t ws_size,
                              hipStream_t stream) {
  const float* x  = (const float*)d_in[0];
  const float* wg = (const float*)d_in[1];
  const float* wu = (const float*)d_in[2];
  const float* wd = (const float*)d_in[3];
  float* out = (float*)d_out;

  const size_t A_BYTES = (size_t)M_TOT * I_DIM * 2;
  const size_t X_BYTES = (size_t)M_TOT * H_DIM * 2;
  const size_t W_BYTES = (size_t)I_DIM * H_DIM * 2;
  char* ws = (char*)d_ws;
  bf16_t* Ab  = (bf16_t*)(ws);
  bf16_t* Xb  = (bf16_t*)(ws + A_BYTES);
  bf16_t* Wgb = (bf16_t*)(ws + A_BYTES + X_BYTES);
  bf16_t* Wub = (bf16_t*)(ws + A_BYTES + X_BYTES + W_BYTES);
  bf16_t* Wdb = Wgb;   // reuse after k_gateup8 consumed Wgb

  const long nX = (long)M_TOT * H_DIM / 4;
  const long nW = (long)I_DIM * H_DIM / 4;

  k_conv<<<dim3(2048), dim3(256), 0, stream>>>((const float4*)x,  (bf16x4*)Xb,  nX);
  k_conv<<<dim3(2048), dim3(256), 0, stream>>>((const float4*)wg, (bf16x4*)Wgb, nW);
  k_conv<<<dim3(2048), dim3(256), 0, stream>>>((const float4*)wu, (bf16x4*)Wub, nW);

  k_gateup8<<<dim3(16 * 112), dim3(512), 0, stream>>>(Xb, Wgb, Wub, Ab);

  k_conv<<<dim3(2048), dim3(256), 0, stream>>>((const float4*)wd, (bf16x4*)Wdb, nW);

  k_down8<<<dim3(16 * 16), dim3(512), 0, stream>>>(Ab, Wdb, out);
}

// Round 5
// 1439.360 us; speedup vs baseline: 1.1474x; 1.1474x over previous
//
#include <hip/hip_runtime.h>
#include <hip/hip_bf16.h>
#include <stdint.h>

typedef __bf16 bf16_t;
typedef __bf16 bf16x4 __attribute__((ext_vector_type(4)));
typedef __bf16 bf16x8 __attribute__((ext_vector_type(8)));
typedef float f32x4 __attribute__((ext_vector_type(4)));

#define LDS_CAST(p) ((__attribute__((address_space(3))) void*)(p))
#define GLB_CAST(p) ((const __attribute__((address_space(1))) void*)(p))

__device__ __forceinline__ void gl_lds16(const void* g, void* l) {
  __builtin_amdgcn_global_load_lds(GLB_CAST(g), LDS_CAST(l), 16, 0, 0);
}

#define MFMA16(a,b,c) __builtin_amdgcn_mfma_f32_16x16x32_bf16((a),(b),(c),0,0,0)
#define BARRIER() __builtin_amdgcn_s_barrier()

template<int N> __device__ __forceinline__ void vmw() {
  if constexpr (N == 8)      asm volatile("s_waitcnt vmcnt(8)" ::: "memory");
  else if constexpr (N == 6) asm volatile("s_waitcnt vmcnt(6)" ::: "memory");
  else if constexpr (N == 4) asm volatile("s_waitcnt vmcnt(4)" ::: "memory");
  else if constexpr (N == 0) asm volatile("s_waitcnt vmcnt(0)" ::: "memory");
}

static constexpr int M_TOT = 4096, H_DIM = 4096, I_DIM = 14336;

// ---------------------------------------------------------------------------
// fp32 -> bf16 conversion (float4 in, bf16x4 out), grid-stride
// ---------------------------------------------------------------------------
__global__ __launch_bounds__(256)
void k_conv(const float4* __restrict__ src, bf16x4* __restrict__ dst, long n4)
{
  long stride = (long)gridDim.x * blockDim.x;
  for (long i = (long)blockIdx.x * blockDim.x + threadIdx.x; i < n4; i += stride) {
    float4 v = src[i];
    bf16x4 o;
    o[0] = (bf16_t)v.x; o[1] = (bf16_t)v.y; o[2] = (bf16_t)v.z; o[3] = (bf16_t)v.w;
    dst[i] = o;
  }
}

// ===========================================================================
// GEMM1: A[M,I] = silu(X Wg^T) * (X Wu^T). BM=256, BN=128, BK=32.
// 8 waves (2M x 4N); 16x16x32 MFMA; 4 LDS bufs x 32 KiB (X 16K | G 8K | U 8K),
// lead-3 staging; ONE barrier + ONE vmcnt(6) per K-tile; compiler-managed
// fine-grained lgkmcnt. Swizzle: stored colb ^= row_bit3<<5 (src pre-XOR'd).
// ===========================================================================
__global__ __launch_bounds__(512, 2)
void k_gateup8(const bf16_t* __restrict__ X, const bf16_t* __restrict__ Wg,
               const bf16_t* __restrict__ Wu, bf16_t* __restrict__ Aout)
{
  __shared__ __align__(1024) char lds[131072];
  const int tid = threadIdx.x, wave = tid >> 6, lane = tid & 63;
  const int lr = lane & 15, kg = lane >> 4;
  const int xm = ((lr >> 3) & 1) << 5;
  const int wm = wave >> 2, wn = wave & 3;

  // tn-major XCD mapping: 16 consecutive blocks on an XCD share one tn
  const int bid = blockIdx.x;                 // grid = 1792
  const int i8  = bid >> 3;                   // 0..223
  const int tn  = (bid & 7) * 14 + (i8 >> 4); // 0..111
  const int tm  = i8 & 15;                    // 0..15

  const int srow  = tid >> 2;                                   // 0..127
  const int scolb = ((tid & 3) * 16) ^ (((tid >> 5) & 1) << 5);

  const bf16_t* gX = X  + (size_t)(tm * 256 + srow) * H_DIM + (scolb >> 1);
  const bf16_t* gG = Wg + (size_t)(tn * 128 + srow) * H_DIM + (scolb >> 1);
  const bf16_t* gU = Wu + (size_t)(tn * 128 + srow) * H_DIM + (scolb >> 1);
  const size_t xh = (size_t)128 * H_DIM;

  const int ck   = (kg * 16) ^ xm;
  const int offA = (wm * 128 + lr) * 64 + ck;            // + f*1024, f=0..7
  const int offG = 16384 + (wn * 32 + lr) * 64 + ck;     // + n*1024, n=0..1
  const int offU = offG + 8192;

  const f32x4 vz = {0.f, 0.f, 0.f, 0.f};
  f32x4 accg[8][2], accu[8][2];
#pragma unroll
  for (int m = 0; m < 8; ++m)
#pragma unroll
    for (int n = 0; n < 2; ++n) { accg[m][n] = vz; accu[m][n] = vz; }

  // prologue: stage tiles 0..2
#pragma unroll
  for (int t = 0; t < 3; ++t) {
    char* lb = lds + t * 32768 + wave * 1024;
    gl_lds16(gX + t * 32,      lb);
    gl_lds16(gX + xh + t * 32, lb + 8192);
    gl_lds16(gG + t * 32,      lb + 16384);
    gl_lds16(gU + t * 32,      lb + 24576);
  }
  vmw<8>(); BARRIER();

#define G1_TILE(T, DO_STG, WAITN, DO_BAR)                                    \
  {                                                                          \
    const char* bb = lds + (((T) & 3) << 15);                                \
    if (DO_STG) {                                                            \
      char* sb = lds + ((((T) + 3) & 3) << 15) + wave * 1024;                \
      const int kc = ((T) + 3) * 32;                                         \
      gl_lds16(gX + kc,      sb);                                            \
      gl_lds16(gX + xh + kc, sb + 8192);                                     \
      gl_lds16(gG + kc,      sb + 16384);                                    \
      gl_lds16(gU + kc,      sb + 24576);                                    \
    }                                                                        \
    bf16x8 bg[2], bu[2], a[8];                                               \
    _Pragma("unroll") for (int n = 0; n < 2; ++n) {                          \
      bg[n] = *(const bf16x8*)(bb + offG + n * 1024);                        \
      bu[n] = *(const bf16x8*)(bb + offU + n * 1024); }                      \
    _Pragma("unroll") for (int f = 0; f < 8; ++f)                            \
      a[f] = *(const bf16x8*)(bb + offA + f * 1024);                         \
    __builtin_amdgcn_s_setprio(1);                                           \
    _Pragma("unroll") for (int m = 0; m < 8; ++m)                            \
    _Pragma("unroll") for (int n = 0; n < 2; ++n) {                          \
      accg[m][n] = MFMA16(a[m], bg[n], accg[m][n]);                          \
      accu[m][n] = MFMA16(a[m], bu[n], accu[m][n]); }                        \
    __builtin_amdgcn_s_setprio(0);                                           \
    vmw<WAITN>();                                                            \
    if (DO_BAR) BARRIER();                                                   \
  }

  const int NT = H_DIM / 32;                  // 128
  for (int T = 0; T <= NT - 4; ++T)
    G1_TILE(T, true, 6, true);
  G1_TILE(NT - 3, false, 4, true);
  G1_TILE(NT - 2, false, 0, true);
  G1_TILE(NT - 1, false, 8 /*no-op? N=8 emits wait; use none*/, false);
#undef G1_TILE

  // epilogue: C/D col = lane&15, row = (lane>>4)*4 + e
  const int r0 = tm * 256 + wm * 128 + kg * 4;
  const int c0 = tn * 128 + wn * 32 + lr;
#pragma unroll
  for (int m = 0; m < 8; ++m)
#pragma unroll
    for (int n = 0; n < 2; ++n)
#pragma unroll
      for (int e = 0; e < 4; ++e) {
        float g = accg[m][n][e];
        float u = accu[m][n][e];
        float s = g / (1.0f + __expf(-g));
        Aout[(size_t)(r0 + m * 16 + e) * I_DIM + c0 + n * 16] = (bf16_t)(s * u);
      }
}

// ===========================================================================
// GEMM2: D[M,H] = A Wd^T. BM=BN=256, BK=32, K=I_DIM. Per-wave 128x64.
// Same 1-barrier/1-vmcnt pipeline. 4 bufs x 32 KiB (A0 8K | A1 8K | B 16K).
// ===========================================================================
__global__ __launch_bounds__(512, 2)
void k_down8(const bf16_t* __restrict__ Aa, const bf16_t* __restrict__ Wd,
             float* __restrict__ D)
{
  __shared__ __align__(1024) char lds[131072];
  const int tid = threadIdx.x, wave = tid >> 6, lane = tid & 63;
  const int lr = lane & 15, kg = lane >> 4;
  const int xm = ((lr >> 3) & 1) << 5;
  const int wm = wave >> 2, wn = wave & 3;

  const int bid = blockIdx.x;                 // grid = 256
  const int i8  = bid >> 3;                   // 0..31
  const int tn  = (bid & 7) * 2 + (i8 >> 4);  // 0..15
  const int tm  = i8 & 15;                    // 0..15

  const int srow  = tid >> 2;
  const int scolb = ((tid & 3) * 16) ^ (((tid >> 5) & 1) << 5);

  const bf16_t* gA = Aa + (size_t)(tm * 256 + srow) * I_DIM + (scolb >> 1);
  const bf16_t* gB = Wd + (size_t)(tn * 256 + srow) * I_DIM + (scolb >> 1);
  const size_t hI = (size_t)128 * I_DIM;

  const int ck   = (kg * 16) ^ xm;
  const int offA = (wm * 128 + lr) * 64 + ck;            // + f*1024
  const int offB = 16384 + (wn * 64 + lr) * 64 + ck;     // + n*1024, n=0..3

  const f32x4 vz = {0.f, 0.f, 0.f, 0.f};
  f32x4 acc[8][4];
#pragma unroll
  for (int m = 0; m < 8; ++m)
#pragma unroll
    for (int n = 0; n < 4; ++n) acc[m][n] = vz;

#pragma unroll
  for (int t = 0; t < 3; ++t) {
    char* lb = lds + t * 32768 + wave * 1024;
    gl_lds16(gA + t * 32,      lb);
    gl_lds16(gA + hI + t * 32, lb + 8192);
    gl_lds16(gB + t * 32,      lb + 16384);
    gl_lds16(gB + hI + t * 32, lb + 24576);
  }
  vmw<8>(); BARRIER();

#define G2_TILE(T, DO_STG, WAITN, DO_BAR)                                    \
  {                                                                          \
    const char* bb = lds + (((T) & 3) << 15);                                \
    if (DO_STG) {                                                            \
      char* sb = lds + ((((T) + 3) & 3) << 15) + wave * 1024;                \
      const int kc = ((T) + 3) * 32;                                         \
      gl_lds16(gA + kc,      sb);                                            \
      gl_lds16(gA + hI + kc, sb + 8192);                                     \
      gl_lds16(gB + kc,      sb + 16384);                                    \
      gl_lds16(gB + hI + kc, sb + 24576);                                    \
    }                                                                        \
    bf16x8 b[4], a[8];                                                       \
    _Pragma("unroll") for (int n = 0; n < 4; ++n)                            \
      b[n] = *(const bf16x8*)(bb + offB + n * 1024);                         \
    _Pragma("unroll") for (int f = 0; f < 8; ++f)                            \
      a[f] = *(const bf16x8*)(bb + offA + f * 1024);                         \
    __builtin_amdgcn_s_setprio(1);                                           \
    _Pragma("unroll") for (int m = 0; m < 8; ++m)                            \
    _Pragma("unroll") for (int n = 0; n < 4; ++n)                            \
      acc[m][n] = MFMA16(a[m], b[n], acc[m][n]);                             \
    __builtin_amdgcn_s_setprio(0);                                           \
    vmw<WAITN>();                                                            \
    if (DO_BAR) BARRIER();                                                   \
  }

  const int NT = I_DIM / 32;                  // 448
  for (int T = 0; T <= NT - 4; ++T)
    G2_TILE(T, true, 6, true);
  G2_TILE(NT - 3, false, 4, true);
  G2_TILE(NT - 2, false, 0, true);
  G2_TILE(NT - 1, false, 8, false);
#undef G2_TILE

  const int r0 = tm * 256 + wm * 128 + kg * 4;
  const int c0 = tn * 256 + wn * 64 + lr;
#pragma unroll
  for (int m = 0; m < 8; ++m)
#pragma unroll
    for (int n = 0; n < 4; ++n)
#pragma unroll
      for (int e = 0; e < 4; ++e)
        D[(size_t)(r0 + m * 16 + e) * H_DIM + c0 + n * 16] = acc[m][n][e];
}

// ---------------------------------------------------------------------------
extern "C" void kernel_launch(void* const* d_in, const int* in_sizes, int n_in,
                              void* d_out, int out_size, void* d_ws, size_t ws_size,
                              hipStream_t stream) {
  const float* x  = (const float*)d_in[0];
  const float* wg = (const float*)d_in[1];
  const float* wu = (const float*)d_in[2];
  const float* wd = (const float*)d_in[3];
  float* out = (float*)d_out;

  const size_t A_BYTES = (size_t)M_TOT * I_DIM * 2;
  const size_t X_BYTES = (size_t)M_TOT * H_DIM * 2;
  const size_t W_BYTES = (size_t)I_DIM * H_DIM * 2;
  char* ws = (char*)d_ws;
  bf16_t* Ab  = (bf16_t*)(ws);
  bf16_t* Xb  = (bf16_t*)(ws + A_BYTES);
  bf16_t* Wgb = (bf16_t*)(ws + A_BYTES + X_BYTES);
  bf16_t* Wub = (bf16_t*)(ws + A_BYTES + X_BYTES + W_BYTES);
  bf16_t* Wdb = Wgb;   // reuse after k_gateup8 consumed Wgb

  const long nX = (long)M_TOT * H_DIM / 4;
  const long nW = (long)I_DIM * H_DIM / 4;

  k_conv<<<dim3(2048), dim3(256), 0, stream>>>((const float4*)x,  (bf16x4*)Xb,  nX);
  k_conv<<<dim3(2048), dim3(256), 0, stream>>>((const float4*)wg, (bf16x4*)Wgb, nW);
  k_conv<<<dim3(2048), dim3(256), 0, stream>>>((const float4*)wu, (bf16x4*)Wub, nW);

  k_gateup8<<<dim3(16 * 112), dim3(512), 0, stream>>>(Xb, Wgb, Wub, Ab);

  k_conv<<<dim3(2048), dim3(256), 0, stream>>>((const float4*)wd, (bf16x4*)Wdb, nW);

  k_down8<<<dim3(16 * 16), dim3(512), 0, stream>>>(Ab, Wdb, out);
}